// Round 10
// baseline (195.180 us; speedup 1.0000x reference)
//
#include <hip/hip_runtime.h>
#include <hip/hip_bf16.h>

#define BATCH   16384
#define NSTEPS  100
#define DT_     0.01f
#define SQRTDT  0.1f
#define SIGMA0_ 0.5f

typedef _Float16  f16x2  __attribute__((ext_vector_type(2)));
typedef _Float16  f16x4  __attribute__((ext_vector_type(4)));
typedef _Float16  f16x8  __attribute__((ext_vector_type(8)));
typedef __fp16    h16x2  __attribute__((ext_vector_type(2)));
typedef float     f32x4  __attribute__((ext_vector_type(4)));

__global__ void zero_out_kernel(float* out) { if (threadIdx.x == 0) out[0] = 0.0f; }

static __device__ __forceinline__ f16x4 pk4(const f32x4& d) {
    union { h16x2 h[2]; f16x4 v; } c;
    c.h[0] = __builtin_amdgcn_cvt_pkrtz(d[0], d[1]);
    c.h[1] = __builtin_amdgcn_cvt_pkrtz(d[2], d[3]);
    return c.v;
}

struct N3 { float a, b, c; };
union HU { unsigned short u; _Float16 h; };

// R10: 3 waves/SIMD via z-MLP n-split. R9 closed the book on memory; the
// floor is issue-port fill (~51% with 2 correlated waves/SIMD). z layers
// 2/3 are linear in output-n: zA owns n=0..31, zB owns n=32..63, each with
// half the W2 frags + one L3 MFMA. r = rA + rB: zB publishes rB(i) to a
// full-depth ring (flag/4); zA folds it batched. q unchanged (recurrence
// can't split). Dep chain acyclic q->zB->zA, full-depth rings, no
// backpressure, deadlock-free. y published as f16 (only consumed as f16).
// 192-thread blocks (zA,zB,q) x 1024; ~35.5KB LDS -> 4 blocks/CU = 12
// waves/CU = 3/SIMD. Total MFMA unchanged; VALU +~10% (h1 dup in zB).
__launch_bounds__(192, 3)
__global__ void deepbsde_kernel(
    const float* __restrict__ y0,  const float* __restrict__ Y0,
    const float* __restrict__ zW1, const float* __restrict__ zb1,
    const float* __restrict__ zW2, const float* __restrict__ zb2,
    const float* __restrict__ zW3, const float* __restrict__ zb3,
    const float* __restrict__ qW1, const float* __restrict__ qb1,
    const float* __restrict__ qW2, const float* __restrict__ qb2,
    const float* __restrict__ qW3, const float* __restrict__ qb3,
    const float* __restrict__ dW,  const float* __restrict__ dZ,
    float* __restrict__ out)
{
    __shared__ __align__(16) _Float16 tbl[NSTEPS * 128];   // 25.6 KB
    __shared__ unsigned short yh_ring[NSTEPS + 1][16];     // 3.2 KB (f16 y)
    __shared__ float rB_ring[NSTEPS][16];                  // 6.4 KB
    __shared__ float ffin[16], yTfin[16], Bfin[16];
    __shared__ int   flags[2];                             // [0]=q, [1]=zB

    const int tid  = threadIdx.x;
    const int lane = tid & 63;
    const int w    = tid >> 6;        // 0=zA, 1=zB, 2=q
    const int ln15 = lane & 15, q4 = lane >> 4;
    const int pbase = (int)blockIdx.x << 4;   // 16 paths per block

    const float y0v = y0[0], Y0v = Y0[0];
    if (tid < 2) flags[tid] = 0;
    if (tid < 16) { HU hu; hu.h = (_Float16)y0v; yh_ring[0][tid] = hu.u; }

    // ---- one-time t-table (192 threads; identical accumulated arithmetic) ----
    {
        float tt = 0.0f;
        for (int i = 0; i < NSTEPS; ++i) {
            int r = tid - ((i % 3) << 6);
            if (r >= 0 && r < 64) {
                int q4e = r >> 4, mlp_ = (r >> 3) & 1, m = r & 7;
                const float* Wp = mlp_ ? qW1 : zW1;
                const float* bp = mlp_ ? qb1 : zb1;
                int i0 = 2*m, i1 = 2*m + 1;
                int k0 = 32*(i0 >> 3) + 8*q4e + (i0 & 7);
                int k1 = 32*(i1 >> 3) + 8*q4e + (i1 & 7);
                _Float16 th = (_Float16)tt;
                f16x2 A = {(_Float16)Wp[k0], (_Float16)Wp[k1]};
                f16x2 C = {(_Float16)bp[k0], (_Float16)bp[k1]};
                f16x2 tv = {th, th};
                f16x2 v = A*tv + C;
                int idx = (i*4 + q4e)*16 + mlp_*8 + m;
                *(f16x2*)&tbl[idx << 1] = v;
            }
            tt += DT_;
        }
    }
    __syncthreads();   // table + seeds visible; ONLY block-wide sync

    const f16x2 zero2h = {(_Float16)0.0f, (_Float16)0.0f};
    const f16x4 zero4h = {(_Float16)0.0f, (_Float16)0.0f, (_Float16)0.0f, (_Float16)0.0f};
    const int c3 = ln15 & 3;

    auto loadW = [&](int i, N3& d) {
        int ic = (i < NSTEPS) ? i : NSTEPS - 1;
        const float* p = dW + ((size_t)ic * BATCH + pbase + ln15) * 3;
        d.a = p[0]; d.b = p[1]; d.c = p[2];
    };
    auto loadZ = [&](int i, N3& d) {
        int ic = (i < NSTEPS) ? i : NSTEPS - 1;
        const float* p = dZ + ((size_t)ic * BATCH + pbase + ln15) * 3;
        d.a = p[0]; d.b = p[1]; d.c = p[2];
    };

    if (w < 2) {
        // ================= z-half wave (w=0: n 0..31 +bias; w=1: n 32..63) ====
        const int half = w;
        f16x2 B1[8];
#pragma unroll
        for (int m = 0; m < 8; ++m) {
            int i0 = 2*m, i1 = 2*m + 1;
            int k0 = 32*(i0 >> 3) + 8*q4 + (i0 & 7);
            int k1 = 32*(i1 >> 3) + 8*q4 + (i1 & 7);
            B1[m] = (f16x2){(_Float16)zW1[64 + k0], (_Float16)zW1[64 + k1]};
        }
        f16x8 Af[2][2];
#pragma unroll
        for (int tl = 0; tl < 2; ++tl)
#pragma unroll
            for (int f = 0; f < 2; ++f)
#pragma unroll
                for (int j = 0; j < 8; ++j) {
                    int tN = 2*half + tl;
                    int k = 32*f + 8*q4 + j, n = 16*tN + ln15;
                    Af[tl][f][j] = (_Float16)zW2[k*64 + n];
                }
        f32x4 b2v[2];
#pragma unroll
        for (int tl = 0; tl < 2; ++tl)
#pragma unroll
            for (int r = 0; r < 4; ++r)
                b2v[tl][r] = zb2[16*(2*half + tl) + 4*q4 + r];
        f16x8 A3h;
#pragma unroll
        for (int j = 0; j < 8; ++j) {
            int tN = 2*half + (j >> 2);
            int n  = 16*tN + 4*q4 + (j & 3);
            A3h[j] = (_Float16)((c3 < 3) ? SQRTDT * zW3[n*3 + c3] : 0.0f);
        }
        const f32x4 C3b = (half == 0)
            ? (f32x4){SQRTDT*zb3[0], SQRTDT*zb3[1], SQRTDT*zb3[2], 0.0f}
            : (f32x4){0.0f, 0.0f, 0.0f, 0.0f};

        float Ysum = 0.0f, acc = 0.0f;
        _Float16 ya, yb, yc, yd;
        float ra = 0.f, rb = 0.f, rc = 0.f, rd = 0.f;

        auto ybatch = [&](int base) {          // y(base..base+3); needs qflag >= base+4
            volatile int* qf = &flags[0];
            while (*qf < base + 4) { }
            HU h0, h1_, h2, h3;
            h0.u = *(volatile unsigned short*)&yh_ring[base + 0][ln15];
            h1_.u = *(volatile unsigned short*)&yh_ring[base + 1][ln15];
            h2.u = *(volatile unsigned short*)&yh_ring[base + 2][ln15];
            h3.u = *(volatile unsigned short*)&yh_ring[base + 3][ln15];
            ya = h0.h; yb = h1_.h; yc = h2.h; yd = h3.h;
        };
        auto rbatch = [&](int base) {          // rB(base..base+3); needs zBflag >= base+4
            volatile int* bf = &flags[1];
            while (*bf < base + 4) { }
            ra = *(volatile float*)&rB_ring[base + 0][ln15];
            rb = *(volatile float*)&rB_ring[base + 1][ln15];
            rc = *(volatile float*)&rB_ring[base + 2][ln15];
            rd = *(volatile float*)&rB_ring[base + 3][ln15];
        };

        auto zstep = [&](int i, _Float16 yh, const N3& nw, const N3& nz, float rOther) {
            const f16x8* tp = (const f16x8*)(tbl + (i*4 + q4)*32);
            union U8 { f16x8 v; f16x2 h[4]; };
            U8 T0; T0.v = tp[0]; U8 T1; T1.v = tp[1];
            const f16x2 yv = {yh, yh};
            union { f16x2 h[4]; f16x8 v; } b0, b1;
#pragma unroll
            for (int m = 0; m < 4; ++m) {
                b0.h[m] = __builtin_elementwise_max((f16x2)(B1[m]*yv   + T0.h[m]), zero2h);
                b1.h[m] = __builtin_elementwise_max((f16x2)(B1[m+4]*yv + T1.h[m]), zero2h);
            }
            f32x4 d0 = b2v[0];
            d0 = __builtin_amdgcn_mfma_f32_16x16x32_f16(Af[0][0], b0.v, d0, 0, 0, 0);
            d0 = __builtin_amdgcn_mfma_f32_16x16x32_f16(Af[0][1], b1.v, d0, 0, 0, 0);
            f32x4 d1 = b2v[1];
            d1 = __builtin_amdgcn_mfma_f32_16x16x32_f16(Af[1][0], b0.v, d1, 0, 0, 0);
            d1 = __builtin_amdgcn_mfma_f32_16x16x32_f16(Af[1][1], b1.v, d1, 0, 0, 0);
            union { f16x4 q[2]; f16x8 o; } B3;
            B3.q[0] = __builtin_elementwise_max(pk4(d0), zero4h);
            B3.q[1] = __builtin_elementwise_max(pk4(d1), zero4h);
            f32x4 P = C3b;
            P = __builtin_amdgcn_mfma_f32_16x16x32_f16(A3h, B3.o, P, 0, 0, 0);
            float zdw = fmaf(P[2], nw.c, fmaf(P[1], nw.b, P[0]*nw.a));
            float zdz = fmaf(P[2], nz.c, fmaf(P[1], nz.b, P[0]*nz.a));
            Ysum += zdw;
            float rh = zdw - zdz;
            if (half == 0) {
                float r = rh + rOther;
                acc = fmaf(r, r, acc);
            } else {
                if (q4 == 0) *(volatile float*)&rB_ring[i][ln15] = rh;
            }
        };

        N3 w0,w1,w2,w3,w4,w5,w6,w7, z0,z1,z2,z3,z4,z5,z6,z7;
        loadW(0,w0); loadZ(0,z0); loadW(1,w1); loadZ(1,z1);
        loadW(2,w2); loadZ(2,z2); loadW(3,w3); loadZ(3,z3);
        loadW(4,w4); loadZ(4,z4); loadW(5,w5); loadZ(5,z5);
        loadW(6,w6); loadZ(6,z6); loadW(7,w7); loadZ(7,z7);

#pragma unroll 1
        for (int k = 0; k < 12; ++k) {
            int i = 8*k;
            ybatch(i);
            if (half == 0) rbatch(i);
            zstep(i,     ya, w0, z0, ra); loadW(i + 8,  w0); loadZ(i + 8,  z0);
            zstep(i + 1, yb, w1, z1, rb); loadW(i + 9,  w1); loadZ(i + 9,  z1);
            zstep(i + 2, yc, w2, z2, rc); loadW(i + 10, w2); loadZ(i + 10, z2);
            zstep(i + 3, yd, w3, z3, rd); loadW(i + 11, w3); loadZ(i + 11, z3);
            if (half == 1) {
                __builtin_amdgcn_s_waitcnt(0xC07F);            // rB writes landed
                if (lane == 0) *(volatile int*)&flags[1] = i + 4;
            }
            ybatch(i + 4);
            if (half == 0) rbatch(i + 4);
            zstep(i + 4, ya, w4, z4, ra); loadW(i + 12, w4); loadZ(i + 12, z4);
            zstep(i + 5, yb, w5, z5, rb); loadW(i + 13, w5); loadZ(i + 13, z5);
            zstep(i + 6, yc, w6, z6, rc); loadW(i + 14, w6); loadZ(i + 14, z6);
            zstep(i + 7, yd, w7, z7, rd); loadW(i + 15, w7); loadZ(i + 15, z7);
            if (half == 1) {
                __builtin_amdgcn_s_waitcnt(0xC07F);
                if (lane == 0) *(volatile int*)&flags[1] = i + 8;
            }
        }
        // tail: steps 96..99 in slots 0..3
        ybatch(96);
        if (half == 0) rbatch(96);
        zstep(96, ya, w0, z0, ra);
        zstep(97, yb, w1, z1, rb);
        zstep(98, yc, w2, z2, rc);
        zstep(99, yd, w3, z3, rd);

        if (half == 1) {
            __builtin_amdgcn_s_waitcnt(0xC07F);
            if (lane == 0) *(volatile int*)&flags[1] = NSTEPS;
            if (q4 == 0) *(volatile float*)&Bfin[ln15] = Ysum;
            __builtin_amdgcn_s_waitcnt(0xC07F);
            if (lane == 0) *(volatile int*)&flags[1] = NSTEPS + 1;
        } else {
            // terminal: need q finals (flag0 = N+1) and zB finals (flag1 = N+1)
            { volatile int* qf = &flags[0]; while (*qf < NSTEPS + 1) { } }
            { volatile int* bf = &flags[1]; while (*bf < NSTEPS + 1) { } }
            float Fq    = *(volatile float*)&ffin[ln15];
            float YsumB = *(volatile float*)&Bfin[ln15];
            float yT    = *(volatile float*)&yTfin[ln15];
            float Yvf = Y0v + Fq + (Ysum + YsumB);
            float dterm = Yvf - yT*yT;
            acc = fmaf(dterm, dterm, acc);

            float val = (q4 == 0) ? acc : 0.0f;
#pragma unroll
            for (int off = 1; off < 64; off <<= 1) val += __shfl_xor(val, off);
            if (lane == 0) atomicAdd(out, val * (1.0f / BATCH));
        }
    } else {
        // ================= q-wave: owns y-recurrence; publish-only ============
        __builtin_amdgcn_s_setprio(1);
        f16x2 B1[8];
#pragma unroll
        for (int m = 0; m < 8; ++m) {
            int i0 = 2*m, i1 = 2*m + 1;
            int k0 = 32*(i0 >> 3) + 8*q4 + (i0 & 7);
            int k1 = 32*(i1 >> 3) + 8*q4 + (i1 & 7);
            B1[m] = (f16x2){(_Float16)qW1[64 + k0], (_Float16)qW1[64 + k1]};
        }
        f16x8 Af[4][2];
#pragma unroll
        for (int tN = 0; tN < 4; ++tN)
#pragma unroll
            for (int f = 0; f < 2; ++f)
#pragma unroll
                for (int j = 0; j < 8; ++j) {
                    int k = 32*f + 8*q4 + j, n = 16*tN + ln15;
                    Af[tN][f][j] = (_Float16)qW2[k*64 + n];
                }
        f32x4 b2v[4];
#pragma unroll
        for (int tN = 0; tN < 4; ++tN)
#pragma unroll
            for (int r = 0; r < 4; ++r)
                b2v[tN][r] = qb2[16*tN + 4*q4 + r];
        f16x8 A3q[2];
#pragma unroll
        for (int fl = 0; fl < 2; ++fl)
#pragma unroll
            for (int j = 0; j < 8; ++j) {
                int tN = 2*fl + (j >> 2);
                int n  = 16*tN + 4*q4 + (j & 3);
                A3q[fl][j] = (_Float16)((c3 == 3) ? qW3[n] : 0.0f);
            }
        const f32x4 C3bq = {0.0f, 0.0f, 0.0f, qb3[0]};
        const float CSIG = SIGMA0_ * SQRTDT;
        const float NHDT = -0.5f * DT_;

        float y = y0v, Facc = 0.0f;

        auto qstep = [&](int j, const N3& nw) {
            const f16x8* tp = (const f16x8*)(tbl + (j*4 + q4)*32);
            union U8 { f16x8 v; f16x2 h[4]; };
            U8 T0; T0.v = tp[2]; U8 T1; T1.v = tp[3];
            _Float16 yh = (_Float16)y;
            const f16x2 yv = {yh, yh};
            union { f16x2 h[4]; f16x8 v; } b0, b1;
#pragma unroll
            for (int m = 0; m < 4; ++m) {
                b0.h[m] = __builtin_elementwise_max((f16x2)(B1[m]*yv   + T0.h[m]), zero2h);
                b1.h[m] = __builtin_elementwise_max((f16x2)(B1[m+4]*yv + T1.h[m]), zero2h);
            }
            union { f16x4 q[4]; f16x8 o[2]; } Bh;
#pragma unroll
            for (int tN = 0; tN < 4; ++tN) {
                f32x4 d = b2v[tN];
                d = __builtin_amdgcn_mfma_f32_16x16x32_f16(Af[tN][0], b0.v, d, 0, 0, 0);
                d = __builtin_amdgcn_mfma_f32_16x16x32_f16(Af[tN][1], b1.v, d, 0, 0, 0);
                Bh.q[tN] = __builtin_elementwise_max(pk4(d), zero4h);
            }
            f32x4 Pv = C3bq;
            Pv = __builtin_amdgcn_mfma_f32_16x16x32_f16(A3q[0], Bh.o[0], Pv, 0, 0, 0);
            Pv = __builtin_amdgcn_mfma_f32_16x16x32_f16(A3q[1], Bh.o[1], Pv, 0, 0, 0);

            float qv = Pv[3];
            float snw = (nw.a + nw.b) + nw.c;
            Facc = fmaf(NHDT*qv, qv, Facc);
            y = fmaf(CSIG, snw, fmaf(qv, DT_, y));
            if (q4 == 0) {
                HU hu; hu.h = (_Float16)y;
                *(volatile unsigned short*)&yh_ring[j + 1][ln15] = hu.u;
            }
        };

        N3 n0,n1,n2,n3,n4,n5,n6,n7;
        loadW(0,n0); loadW(1,n1); loadW(2,n2); loadW(3,n3);
        loadW(4,n4); loadW(5,n5); loadW(6,n6); loadW(7,n7);

#pragma unroll 1
        for (int k = 0; k < 12; ++k) {
            int j = 8*k;
            qstep(j,     n0);  loadW(j + 8,  n0);
            qstep(j + 1, n1);  loadW(j + 9,  n1);
            qstep(j + 2, n2);  loadW(j + 10, n2);
            qstep(j + 3, n3);  loadW(j + 11, n3);
            __builtin_amdgcn_s_waitcnt(0xC07F);        // y writes landed
            if (lane == 0) *(volatile int*)&flags[0] = j + 4;
            qstep(j + 4, n4);  loadW(j + 12, n4);
            qstep(j + 5, n5);  loadW(j + 13, n5);
            qstep(j + 6, n6);  loadW(j + 14, n6);
            qstep(j + 7, n7);  loadW(j + 15, n7);
            __builtin_amdgcn_s_waitcnt(0xC07F);
            if (lane == 0) *(volatile int*)&flags[0] = j + 8;
        }
        // tail: steps 96..99 in slots 0..3
        qstep(96, n0);
        qstep(97, n1);
        qstep(98, n2);
        qstep(99, n3);
        __builtin_amdgcn_s_waitcnt(0xC07F);            // y(100) landed
        if (lane == 0) *(volatile int*)&flags[0] = NSTEPS;

        if (q4 == 0) {
            *(volatile float*)&ffin[ln15]  = Facc;
            *(volatile float*)&yTfin[ln15] = y;        // y(NSTEPS) in f32
        }
        __builtin_amdgcn_s_waitcnt(0xC07F);
        if (lane == 0) *(volatile int*)&flags[0] = NSTEPS + 1;
    }
}

extern "C" void kernel_launch(void* const* d_in, const int* in_sizes, int n_in,
                              void* d_out, int out_size, void* d_ws, size_t ws_size,
                              hipStream_t stream)
{
    zero_out_kernel<<<1, 64, 0, stream>>>((float*)d_out);
    deepbsde_kernel<<<1024, 192, 0, stream>>>(
        (const float*)d_in[0],  (const float*)d_in[1],
        (const float*)d_in[2],  (const float*)d_in[3],
        (const float*)d_in[4],  (const float*)d_in[5],
        (const float*)d_in[6],  (const float*)d_in[7],
        (const float*)d_in[8],  (const float*)d_in[9],
        (const float*)d_in[10], (const float*)d_in[11],
        (const float*)d_in[12], (const float*)d_in[13],
        (const float*)d_in[14], (const float*)d_in[15],
        (float*)d_out);
}

// Round 11
// 161.283 us; speedup vs baseline: 1.2102x; 1.2102x over previous
//
#include <hip/hip_runtime.h>
#include <hip/hip_bf16.h>

#define BATCH   16384
#define NSTEPS  100
#define DT_     0.01f
#define SQRTDT  0.1f
#define SIGMA0_ 0.5f

typedef _Float16  f16x2  __attribute__((ext_vector_type(2)));
typedef _Float16  f16x4  __attribute__((ext_vector_type(4)));
typedef _Float16  f16x8  __attribute__((ext_vector_type(8)));
typedef __fp16    h16x2  __attribute__((ext_vector_type(2)));
typedef float     f32x4  __attribute__((ext_vector_type(4)));

__global__ void zero_out_kernel(float* out) { if (threadIdx.x == 0) out[0] = 0.0f; }

static __device__ __forceinline__ f16x4 pk4(const f32x4& d) {
    union { h16x2 h[2]; f16x4 v; } c;
    c.h[0] = __builtin_amdgcn_cvt_pkrtz(d[0], d[1]);
    c.h[1] = __builtin_amdgcn_cvt_pkrtz(d[2], d[3]);
    return c.v;
}

struct N3 { float a, b, c; };
union HU { unsigned short u; _Float16 h; };

// R11: R8 structure (z/q decoupled pair, best at 66us) with ALL exposed LDS
// latency removed from the steady loop:
//  - z-wave t-table reads were INLINE at step top in R7-R9 (ds_read_b128 ->
//    immediate lgkmcnt(0) stall every step). Restored R4-style ping-pong
//    prefetch (load step i+1 while computing i).
//  - y consumed in 4-batches prefetched ONE BATCH AHEAD: poll + issue reads
//    for batch b+1 during batch b, so waitcnt lands on arrived data.
//  - q publishes y as f16 (ds_write_b16; z reads ushort directly -- same
//    rounding as its former (f16)y cvt, bit-identical); terminal y(100)
//    passed separately in f32.
//  - noise register-direct 8-deep (R9), no LDS noise rings, no manual vmcnt.
// Roles mixed per SIMD via block flip (free). q at setprio(1).
__launch_bounds__(256, 2)
__global__ void deepbsde_kernel(
    const float* __restrict__ y0,  const float* __restrict__ Y0,
    const float* __restrict__ zW1, const float* __restrict__ zb1,
    const float* __restrict__ zW2, const float* __restrict__ zb2,
    const float* __restrict__ zW3, const float* __restrict__ zb3,
    const float* __restrict__ qW1, const float* __restrict__ qb1,
    const float* __restrict__ qW2, const float* __restrict__ qb2,
    const float* __restrict__ qW3, const float* __restrict__ qb3,
    const float* __restrict__ dW,  const float* __restrict__ dZ,
    float* __restrict__ out)
{
    __shared__ __align__(16) _Float16 tbl[NSTEPS * 128];   // 25.6 KB
    __shared__ unsigned short yh_ring[2][NSTEPS + 1][16];  // 6.5 KB (f16 y)
    __shared__ float ffin[2][16], yTfin[2][16];
    __shared__ int   flags[2];

    const int tid  = threadIdx.x;
    const int lane = tid & 63;
    const int w    = tid >> 6;        // 0..3
    const int g    = w >> 1;          // path group
    const int flip = (((int)blockIdx.x >> 3) ^ ((int)blockIdx.x >> 8)) & 1;
    const bool isQ = ((w & 1) ^ flip) != 0;
    const int ln15 = lane & 15, q4 = lane >> 4;
    const int gw   = (blockIdx.x << 1) + g;
    const int pbase = gw << 4;        // 16 paths per group

    const float y0v = y0[0], Y0v = Y0[0];
    if (tid < 2) flags[tid] = 0;
    if (tid < 32) { HU hu; hu.h = (_Float16)y0v; yh_ring[tid >> 4][0][tid & 15] = hu.u; }

    // ---- one-time t-table (both MLP halves), identical accumulated math ----
    {
        float tt = 0.0f;
        for (int i = 0; i < NSTEPS; ++i) {
            int r = (tid - (i << 6)) & 255;
            if (r < 64) {
                int q4e = r >> 4, mlp_ = (r >> 3) & 1, m = r & 7;
                const float* Wp = mlp_ ? qW1 : zW1;
                const float* bp = mlp_ ? qb1 : zb1;
                int i0 = 2*m, i1 = 2*m + 1;
                int k0 = 32*(i0 >> 3) + 8*q4e + (i0 & 7);
                int k1 = 32*(i1 >> 3) + 8*q4e + (i1 & 7);
                _Float16 th = (_Float16)tt;
                f16x2 A = {(_Float16)Wp[k0], (_Float16)Wp[k1]};
                f16x2 C = {(_Float16)bp[k0], (_Float16)bp[k1]};
                f16x2 tv = {th, th};
                f16x2 v = A*tv + C;
                int idx = (i*4 + q4e)*16 + mlp_*8 + m;
                *(f16x2*)&tbl[idx << 1] = v;
            }
            tt += DT_;
        }
    }

    // ---- role-selected weights ----
    const float* W1p = isQ ? qW1 : zW1;
    const float* W2p = isQ ? qW2 : zW2;
    const float* b2p = isQ ? qb2 : zb2;

    f16x2 B1[8];
#pragma unroll
    for (int m = 0; m < 8; ++m) {
        int i0 = 2*m, i1 = 2*m + 1;
        int k0 = 32*(i0 >> 3) + 8*q4 + (i0 & 7);
        int k1 = 32*(i1 >> 3) + 8*q4 + (i1 & 7);
        B1[m] = (f16x2){(_Float16)W1p[64 + k0], (_Float16)W1p[64 + k1]};
    }
    f16x8 Af[4][2];
#pragma unroll
    for (int tN = 0; tN < 4; ++tN)
#pragma unroll
        for (int f = 0; f < 2; ++f)
#pragma unroll
            for (int j = 0; j < 8; ++j) {
                int k = 32*f + 8*q4 + j, n = 16*tN + ln15;
                Af[tN][f][j] = (_Float16)W2p[k*64 + n];
            }
    f32x4 b2v[4];
#pragma unroll
    for (int tN = 0; tN < 4; ++tN)
#pragma unroll
        for (int r = 0; r < 4; ++r)
            b2v[tN][r] = b2p[16*tN + 4*q4 + r];

    const int c3 = ln15 & 3;
    f16x8 A3[2];
#pragma unroll
    for (int fl = 0; fl < 2; ++fl)
#pragma unroll
        for (int j = 0; j < 8; ++j) {
            int tN = 2*fl + (j >> 2);
            int n  = 16*tN + 4*q4 + (j & 3);
            float wv = isQ ? ((c3 == 3) ? qW3[n]                 : 0.0f)
                           : ((c3 < 3)  ? SQRTDT * zW3[n*3 + c3] : 0.0f);
            A3[fl][j] = (_Float16)wv;
        }
    const f32x4 C3b = isQ ? (f32x4){0.0f, 0.0f, 0.0f, qb3[0]}
                          : (f32x4){SQRTDT*zb3[0], SQRTDT*zb3[1], SQRTDT*zb3[2], 0.0f};

    const float CSIG = SIGMA0_ * SQRTDT;
    const float NHDT = -0.5f * DT_;
    const f16x2 zero2h = {(_Float16)0.0f, (_Float16)0.0f};
    const f16x4 zero4h = {(_Float16)0.0f, (_Float16)0.0f, (_Float16)0.0f, (_Float16)0.0f};

    auto loadW = [&](int i, N3& d) {
        int ic = (i < NSTEPS) ? i : NSTEPS - 1;
        const float* p = dW + ((size_t)ic * BATCH + pbase + ln15) * 3;
        d.a = p[0]; d.b = p[1]; d.c = p[2];
    };
    auto loadZ = [&](int i, N3& d) {
        int ic = (i < NSTEPS) ? i : NSTEPS - 1;
        const float* p = dZ + ((size_t)ic * BATCH + pbase + ln15) * 3;
        d.a = p[0]; d.b = p[1]; d.c = p[2];
    };

    __syncthreads();   // table + flags + y0 visible; ONLY block-wide sync

    if (!isQ) {
        // ========== z-wave: 4-step batches, everything prefetched ==========
        float Ysum = 0.0f, acc = 0.0f;
        f16x8 tc0, tc1, td0, td1;          // t-table ping-pong
        { const f16x8* tp = (const f16x8*)(tbl + q4*32); tc0 = tp[0]; tc1 = tp[1]; }
        unsigned short ya, yb, yc, yd, ea, eb, ec, ed;   // y f16 bits, cur + next

        auto zstep = [&](int i, unsigned short yu, const N3& nw, const N3& nz,
                         f16x8& t0, f16x8& t1, f16x8& u0, f16x8& u1) {
            // prefetch t-table for step i+1 (consumed next call)
            int ip = i + 1; ip = (ip > NSTEPS - 1) ? NSTEPS - 1 : ip;
            { const f16x8* tp = (const f16x8*)(tbl + (ip*4 + q4)*32); u0 = tp[0]; u1 = tp[1]; }

            HU hu; hu.u = yu;
            const f16x2 yv = {hu.h, hu.h};
            union U8 { f16x8 v; f16x2 h[4]; };
            U8 T0; T0.v = t0; U8 T1; T1.v = t1;
            union { f16x2 h[4]; f16x8 v; } b0, b1;
#pragma unroll
            for (int m = 0; m < 4; ++m) {
                b0.h[m] = __builtin_elementwise_max((f16x2)(B1[m]*yv   + T0.h[m]), zero2h);
                b1.h[m] = __builtin_elementwise_max((f16x2)(B1[m+4]*yv + T1.h[m]), zero2h);
            }
            union { f16x4 q[4]; f16x8 o[2]; } Bh;
#pragma unroll
            for (int tN = 0; tN < 4; ++tN) {
                f32x4 d = b2v[tN];
                d = __builtin_amdgcn_mfma_f32_16x16x32_f16(Af[tN][0], b0.v, d, 0, 0, 0);
                d = __builtin_amdgcn_mfma_f32_16x16x32_f16(Af[tN][1], b1.v, d, 0, 0, 0);
                Bh.q[tN] = __builtin_elementwise_max(pk4(d), zero4h);
            }
            f32x4 P = C3b;
            P = __builtin_amdgcn_mfma_f32_16x16x32_f16(A3[0], Bh.o[0], P, 0, 0, 0);
            P = __builtin_amdgcn_mfma_f32_16x16x32_f16(A3[1], Bh.o[1], P, 0, 0, 0);

            float zdw = fmaf(P[2], nw.c, fmaf(P[1], nw.b, P[0]*nw.a));
            float zdz = fmaf(P[2], nz.c, fmaf(P[1], nz.b, P[0]*nz.a));
            Ysum += zdw;
            float r = zdw - zdz;
            acc = fmaf(r, r, acc);
        };

        // prologue: y(0..3) (flag >= 4 covers y(1..3); y(0) seeded)
        {
            volatile int* qf = &flags[g];
            while (*qf < 4) { }
            ya = *(volatile unsigned short*)&yh_ring[g][0][ln15];
            yb = *(volatile unsigned short*)&yh_ring[g][1][ln15];
            yc = *(volatile unsigned short*)&yh_ring[g][2][ln15];
            yd = *(volatile unsigned short*)&yh_ring[g][3][ln15];
        }
        N3 w0,w1,w2,w3,w4,w5,w6,w7, z0,z1,z2,z3,z4,z5,z6,z7;
        loadW(0,w0); loadZ(0,z0); loadW(1,w1); loadZ(1,z1);
        loadW(2,w2); loadZ(2,z2); loadW(3,w3); loadZ(3,z3);
        loadW(4,w4); loadZ(4,z4); loadW(5,w5); loadZ(5,z5);
        loadW(6,w6); loadZ(6,z6); loadW(7,w7); loadZ(7,z7);

#pragma unroll 1
        for (int b = 0; b < 25; ++b) {
            int i = 4*b;
            if (b < 24) {
                // prefetch NEXT batch's y (poll succeeds first read in steady state)
                int need = i + 8; if (need > NSTEPS) need = NSTEPS;
                volatile int* qf = &flags[g];
                while (*qf < need) { }
                ea = *(volatile unsigned short*)&yh_ring[g][i + 4][ln15];
                eb = *(volatile unsigned short*)&yh_ring[g][i + 5][ln15];
                ec = *(volatile unsigned short*)&yh_ring[g][i + 6][ln15];
                ed = *(volatile unsigned short*)&yh_ring[g][i + 7][ln15];
            }
            if ((b & 1) == 0) {
                zstep(i,     ya, w0, z0, tc0, tc1, td0, td1); loadW(i + 8,  w0); loadZ(i + 8,  z0);
                zstep(i + 1, yb, w1, z1, td0, td1, tc0, tc1); loadW(i + 9,  w1); loadZ(i + 9,  z1);
                zstep(i + 2, yc, w2, z2, tc0, tc1, td0, td1); loadW(i + 10, w2); loadZ(i + 10, z2);
                zstep(i + 3, yd, w3, z3, td0, td1, tc0, tc1); loadW(i + 11, w3); loadZ(i + 11, z3);
            } else {
                zstep(i,     ya, w4, z4, tc0, tc1, td0, td1); loadW(i + 8,  w4); loadZ(i + 8,  z4);
                zstep(i + 1, yb, w5, z5, td0, td1, tc0, tc1); loadW(i + 9,  w5); loadZ(i + 9,  z5);
                zstep(i + 2, yc, w6, z6, tc0, tc1, td0, td1); loadW(i + 10, w6); loadZ(i + 10, z6);
                zstep(i + 3, yd, w7, z7, td0, td1, tc0, tc1); loadW(i + 11, w7); loadZ(i + 11, z7);
            }
            ya = ea; yb = eb; yc = ec; yd = ed;
        }

        // terminal: q finals
        { volatile int* qf = &flags[g]; while (*qf < NSTEPS + 1) { } }
        float Fq = *(volatile float*)&ffin[g][ln15];
        float yT = *(volatile float*)&yTfin[g][ln15];
        float Yvf = Y0v + Fq + Ysum;
        float dterm = Yvf - yT*yT;
        acc = fmaf(dterm, dterm, acc);

        float val = (q4 == 0) ? acc : 0.0f;
#pragma unroll
        for (int off = 1; off < 64; off <<= 1) val += __shfl_xor(val, off);
        if (lane == 0) atomicAdd(out, val * (1.0f / BATCH));
    } else {
        // ========== q-wave: serial y-recurrence; publish-only ==========
        __builtin_amdgcn_s_setprio(1);
        float y = y0v, Facc = 0.0f;
        f16x8 c0, c1, d0, d1;
        { const f16x8* tp = (const f16x8*)(tbl + q4*32); c0 = tp[2]; c1 = tp[3]; }

        auto qstep = [&](int j, const N3& nw, f16x8& t0, f16x8& t1, f16x8& u0, f16x8& u1) {
            int jp = j + 1; jp = (jp > NSTEPS - 1) ? NSTEPS - 1 : jp;
            { const f16x8* tp = (const f16x8*)(tbl + (jp*4 + q4)*32); u0 = tp[2]; u1 = tp[3]; }

            _Float16 yh = (_Float16)y;
            const f16x2 yv = {yh, yh};
            union U8 { f16x8 v; f16x2 h[4]; };
            U8 T0; T0.v = t0; U8 T1; T1.v = t1;
            union { f16x2 h[4]; f16x8 v; } b0, b1;
#pragma unroll
            for (int m = 0; m < 4; ++m) {
                b0.h[m] = __builtin_elementwise_max((f16x2)(B1[m]*yv   + T0.h[m]), zero2h);
                b1.h[m] = __builtin_elementwise_max((f16x2)(B1[m+4]*yv + T1.h[m]), zero2h);
            }
            union { f16x4 q[4]; f16x8 o[2]; } Bh;
#pragma unroll
            for (int tN = 0; tN < 4; ++tN) {
                f32x4 d = b2v[tN];
                d = __builtin_amdgcn_mfma_f32_16x16x32_f16(Af[tN][0], b0.v, d, 0, 0, 0);
                d = __builtin_amdgcn_mfma_f32_16x16x32_f16(Af[tN][1], b1.v, d, 0, 0, 0);
                Bh.q[tN] = __builtin_elementwise_max(pk4(d), zero4h);
            }
            f32x4 Pv = C3b;
            Pv = __builtin_amdgcn_mfma_f32_16x16x32_f16(A3[0], Bh.o[0], Pv, 0, 0, 0);
            Pv = __builtin_amdgcn_mfma_f32_16x16x32_f16(A3[1], Bh.o[1], Pv, 0, 0, 0);

            float qv = Pv[3];
            float snw = (nw.a + nw.b) + nw.c;
            Facc = fmaf(NHDT*qv, qv, Facc);
            y = fmaf(CSIG, snw, fmaf(qv, DT_, y));
            if (q4 == 0) {
                HU hu; hu.h = (_Float16)y;
                *(volatile unsigned short*)&yh_ring[g][j + 1][ln15] = hu.u;
            }
        };

        N3 n0,n1,n2,n3,n4,n5,n6,n7;
        loadW(0,n0); loadW(1,n1); loadW(2,n2); loadW(3,n3);
        loadW(4,n4); loadW(5,n5); loadW(6,n6); loadW(7,n7);

#pragma unroll 1
        for (int k = 0; k < 12; ++k) {
            int j = 8*k;
            qstep(j,     n0, c0, c1, d0, d1);  loadW(j + 8,  n0);
            qstep(j + 1, n1, d0, d1, c0, c1);  loadW(j + 9,  n1);
            qstep(j + 2, n2, c0, c1, d0, d1);  loadW(j + 10, n2);
            qstep(j + 3, n3, d0, d1, c0, c1);  loadW(j + 11, n3);
            __builtin_amdgcn_s_waitcnt(0xC07F);        // y writes landed
            if (lane == 0) *(volatile int*)&flags[g] = j + 4;
            qstep(j + 4, n4, c0, c1, d0, d1);  loadW(j + 12, n4);
            qstep(j + 5, n5, d0, d1, c0, c1);  loadW(j + 13, n5);
            qstep(j + 6, n6, c0, c1, d0, d1);  loadW(j + 14, n6);
            qstep(j + 7, n7, d0, d1, c0, c1);  loadW(j + 15, n7);
            __builtin_amdgcn_s_waitcnt(0xC07F);
            if (lane == 0) *(volatile int*)&flags[g] = j + 8;
        }
        // tail: steps 96..99 in slots 0..3
        qstep(96, n0, c0, c1, d0, d1);
        qstep(97, n1, d0, d1, c0, c1);
        qstep(98, n2, c0, c1, d0, d1);
        qstep(99, n3, d0, d1, c0, c1);
        __builtin_amdgcn_s_waitcnt(0xC07F);            // y(100) landed
        if (lane == 0) *(volatile int*)&flags[g] = NSTEPS;

        if (q4 == 0) {
            *(volatile float*)&ffin[g][ln15]  = Facc;
            *(volatile float*)&yTfin[g][ln15] = y;     // y(NSTEPS) in f32
        }
        __builtin_amdgcn_s_waitcnt(0xC07F);
        if (lane == 0) *(volatile int*)&flags[g] = NSTEPS + 1;
    }
}

extern "C" void kernel_launch(void* const* d_in, const int* in_sizes, int n_in,
                              void* d_out, int out_size, void* d_ws, size_t ws_size,
                              hipStream_t stream)
{
    zero_out_kernel<<<1, 64, 0, stream>>>((float*)d_out);
    deepbsde_kernel<<<512, 256, 0, stream>>>(
        (const float*)d_in[0],  (const float*)d_in[1],
        (const float*)d_in[2],  (const float*)d_in[3],
        (const float*)d_in[4],  (const float*)d_in[5],
        (const float*)d_in[6],  (const float*)d_in[7],
        (const float*)d_in[8],  (const float*)d_in[9],
        (const float*)d_in[10], (const float*)d_in[11],
        (const float*)d_in[12], (const float*)d_in[13],
        (const float*)d_in[14], (const float*)d_in[15],
        (float*)d_out);
}